// Round 1
// baseline (57.289 us; speedup 1.0000x reference)
//
#include <hip/hip_runtime.h>
#include <hip/hip_bf16.h>

typedef __bf16 bf16x8 __attribute__((ext_vector_type(8)));
typedef __bf16 bf16x4 __attribute__((ext_vector_type(4)));
typedef float  f32x4  __attribute__((ext_vector_type(4)));
typedef unsigned short u16;

static constexpr int N = 8192;
static constexpr int D = 32;
static constexpr int NSPLIT = 4;          // K-split across blocks
static constexpr int KPB = N / NSPLIT;    // 2048 keys per block
static constexpr int STAGE = 64;          // keys staged in LDS per iter
static constexpr float L2E = 1.44269504088896340736f;

// ---------------- pre-pass: fp32 -> bf16 (RNE) for Q, K, V ----------------
__global__ __launch_bounds__(256) void cvt_bf16_kernel(
    const float* __restrict__ Q, const float* __restrict__ K,
    const float* __restrict__ V, u16* __restrict__ Qb, u16* __restrict__ Kb,
    u16* __restrict__ Vb) {
  const int i = (blockIdx.x * 256 + threadIdx.x) * 4;
  if (i >= N * D) return;
  const float4 q = *reinterpret_cast<const float4*>(Q + i);
  const float4 k = *reinterpret_cast<const float4*>(K + i);
  const float4 v = *reinterpret_cast<const float4*>(V + i);
  auto pack = [](float a, float b) -> unsigned int {
    u16 ua = __builtin_bit_cast(u16, (__bf16)a);
    u16 ub = __builtin_bit_cast(u16, (__bf16)b);
    return (unsigned int)ua | ((unsigned int)ub << 16);
  };
  uint2 qo = { pack(q.x, q.y), pack(q.z, q.w) };
  uint2 ko = { pack(k.x, k.y), pack(k.z, k.w) };
  uint2 vo = { pack(v.x, v.y), pack(v.z, v.w) };
  *reinterpret_cast<uint2*>(Qb + i) = qo;
  *reinterpret_cast<uint2*>(Kb + i) = ko;
  *reinterpret_cast<uint2*>(Vb + i) = vo;
}

// ---------------- main flash kernel ----------------
// grid: (N/64 q-groups) * NSPLIT blocks, 256 threads (4 waves).
// Each wave owns one 16-row Q tile; block processes keys [sp*KPB, sp*KPB+KPB).
// S^T-tile = mfma(A=K-frag, B=Q-frag): D[k][q], k-row = 4*(l>>4)+r (+16h),
// q-col = l&15 (verified C/D layout). P stays in regs and feeds PV MFMA as the
// B operand with slot i <-> k = 4g + (i&3) + 16*(i>>2), matched by the V^T
// A-fragment read from LDS with the same map.
__global__ __launch_bounds__(256) void flash_kernel(
    const u16* __restrict__ Qb, const u16* __restrict__ Kb,
    const u16* __restrict__ Vb, float* __restrict__ mP, float* __restrict__ lP,
    float* __restrict__ OP) {
  __shared__ u16 Vt[32][68];  // V^T for current stage: [d][key], pad 64->68 (8B align + bank spread)

  const int lane = threadIdx.x & 63;
  const int wave = threadIdx.x >> 6;
  const int a = lane & 15;   // row-in-tile / q-col
  const int g = lane >> 4;   // lane group 0..3
  const int qg = blockIdx.x >> 2;        // 0..127
  const int sp = blockIdx.x & (NSPLIT - 1);
  const int qr0 = qg * 64 + wave * 16;
  const int k0 = sp * KPB;

  // Q fragment: lane holds Q[qr0 + a][8g .. 8g+7] (contiguous-k map; any
  // bijection works since K-frag uses the same one).
  const bf16x8 qf = *reinterpret_cast<const bf16x8*>(Qb + (qr0 + a) * D + g * 8);

  const f32x4 zero4 = {0.f, 0.f, 0.f, 0.f};
  f32x4 acc0 = zero4, acc1 = zero4;  // O^T tiles: d in [0,16), [16,32)
  float mrun = -INFINITY;            // running max, log2 domain
  float lsum = 0.f;

  const int sk = threadIdx.x & 63;   // staging: key within stage
  const int dgr = threadIdx.x >> 6;  // staging: d-group (8 dims)

  for (int kb = k0; kb < k0 + KPB; kb += STAGE) {
    __syncthreads();  // previous-stage compute done before overwrite
    {
      const uint4 vv = *reinterpret_cast<const uint4*>(Vb + (kb + sk) * D + dgr * 8);
      const unsigned int w[4] = {vv.x, vv.y, vv.z, vv.w};
#pragma unroll
      for (int j = 0; j < 4; ++j) {
        Vt[dgr * 8 + 2 * j][sk]     = (u16)(w[j] & 0xffffu);
        Vt[dgr * 8 + 2 * j + 1][sk] = (u16)(w[j] >> 16);
      }
    }
    __syncthreads();

#pragma unroll
    for (int u = 0; u < 2; ++u) {   // two 32-key units per stage
      const int kk = kb + u * 32;
      const bf16x8 kf0 = *reinterpret_cast<const bf16x8*>(Kb + (kk + a) * D + g * 8);
      const bf16x8 kf1 = *reinterpret_cast<const bf16x8*>(Kb + (kk + 16 + a) * D + g * 8);
      f32x4 s0 = __builtin_amdgcn_mfma_f32_16x16x32_bf16(kf0, qf, zero4, 0, 0, 0);
      f32x4 s1 = __builtin_amdgcn_mfma_f32_16x16x32_bf16(kf1, qf, zero4, 0, 0, 0);
      s0 *= L2E;  // log2 domain
      s1 *= L2E;
      float tm = fmaxf(fmaxf(fmaxf(s0[0], s0[1]), fmaxf(s0[2], s0[3])),
                       fmaxf(fmaxf(s1[0], s1[1]), fmaxf(s1[2], s1[3])));
      tm = fmaxf(tm, __shfl_xor(tm, 16, 64));
      tm = fmaxf(tm, __shfl_xor(tm, 32, 64));
      const float mnew = fmaxf(mrun, tm);
      const float sc = __builtin_amdgcn_exp2f(mrun - mnew);  // first iter: 2^-inf = 0
      mrun = mnew;
      float p[8];
#pragma unroll
      for (int j = 0; j < 4; ++j) p[j] = __builtin_amdgcn_exp2f(s0[j] - mnew);
#pragma unroll
      for (int j = 0; j < 4; ++j) p[4 + j] = __builtin_amdgcn_exp2f(s1[j] - mnew);
      float ps = ((p[0] + p[1]) + (p[2] + p[3])) + ((p[4] + p[5]) + (p[6] + p[7]));
      ps += __shfl_xor(ps, 16, 64);
      ps += __shfl_xor(ps, 32, 64);
      lsum = lsum * sc + ps;
      acc0 *= sc;
      acc1 *= sc;
      const bf16x8 pf = {(__bf16)p[0], (__bf16)p[1], (__bf16)p[2], (__bf16)p[3],
                         (__bf16)p[4], (__bf16)p[5], (__bf16)p[6], (__bf16)p[7]};
      // V^T fragments: lane l -> V^T[16h + a][u*32 + 4g + (i&3) + 16*(i>>2)]
      const int c0 = u * 32 + g * 4;
      const bf16x4 v00 = *reinterpret_cast<const bf16x4*>(&Vt[a][c0]);
      const bf16x4 v01 = *reinterpret_cast<const bf16x4*>(&Vt[a][c0 + 16]);
      const bf16x4 v10 = *reinterpret_cast<const bf16x4*>(&Vt[16 + a][c0]);
      const bf16x4 v11 = *reinterpret_cast<const bf16x4*>(&Vt[16 + a][c0 + 16]);
      const bf16x8 va0 = __builtin_shufflevector(v00, v01, 0, 1, 2, 3, 4, 5, 6, 7);
      const bf16x8 va1 = __builtin_shufflevector(v10, v11, 0, 1, 2, 3, 4, 5, 6, 7);
      acc0 = __builtin_amdgcn_mfma_f32_16x16x32_bf16(va0, pf, acc0, 0, 0, 0);
      acc1 = __builtin_amdgcn_mfma_f32_16x16x32_bf16(va1, pf, acc1, 0, 0, 0);
    }
  }

  // store partials: O^T lane holds O[d = 16h + 4g + r][q = qr0 + a]
  float* obase = OP + (size_t)(sp * N + qr0 + a) * D;
#pragma unroll
  for (int r = 0; r < 4; ++r) {
    obase[4 * g + r] = acc0[r];
    obase[16 + 4 * g + r] = acc1[r];
  }
  if (g == 0) {
    mP[sp * N + qr0 + a] = mrun;
    lP[sp * N + qr0 + a] = lsum;
  }
}

// ---------------- combine splits ----------------
__global__ __launch_bounds__(256) void combine_kernel(
    const float* __restrict__ mP, const float* __restrict__ lP,
    const float* __restrict__ OP, float* __restrict__ out) {
  const int idx = blockIdx.x * 256 + threadIdx.x;
  if (idx >= N * D) return;
  const int q = idx >> 5;
  float m[NSPLIT];
  float M = -INFINITY;
#pragma unroll
  for (int s = 0; s < NSPLIT; ++s) {
    m[s] = mP[s * N + q];
    M = fmaxf(M, m[s]);
  }
  float L = 0.f, o = 0.f;
#pragma unroll
  for (int s = 0; s < NSPLIT; ++s) {
    const float w = __builtin_amdgcn_exp2f(m[s] - M);
    L += w * lP[s * N + q];
    o += w * OP[(size_t)s * N * D + idx];
  }
  out[idx] = o / L;
}

extern "C" void kernel_launch(void* const* d_in, const int* in_sizes, int n_in,
                              void* d_out, int out_size, void* d_ws, size_t ws_size,
                              hipStream_t stream) {
  const float* Q = (const float*)d_in[0];
  const float* K = (const float*)d_in[1];
  const float* V = (const float*)d_in[2];
  float* out = (float*)d_out;

  // ws layout
  u16* Qb = (u16*)d_ws;
  u16* Kb = Qb + N * D;
  u16* Vb = Kb + N * D;
  float* mP = (float*)(Vb + N * D);
  float* lP = mP + NSPLIT * N;
  float* OP = lP + NSPLIT * N;

  cvt_bf16_kernel<<<(N * D) / (256 * 4), 256, 0, stream>>>(Q, K, V, Qb, Kb, Vb);
  flash_kernel<<<(N / 64) * NSPLIT, 256, 0, stream>>>(Qb, Kb, Vb, mP, lP, OP);
  combine_kernel<<<(N * D) / 256, 256, 0, stream>>>(mP, lP, OP, out);
}

// Round 2
// 52.185 us; speedup vs baseline: 1.0978x; 1.0978x over previous
//
#include <hip/hip_runtime.h>
#include <hip/hip_bf16.h>

typedef __bf16 bf16x8 __attribute__((ext_vector_type(8)));
typedef __bf16 bf16x4 __attribute__((ext_vector_type(4)));
typedef float  f32x4  __attribute__((ext_vector_type(4)));
typedef unsigned short u16;

static constexpr int N = 8192;
static constexpr int D = 32;
static constexpr float L2E = 1.44269504088896340736f;

// ---------------- pre-pass: fp32 -> bf16 (RNE) for Q, K, V ----------------
__global__ __launch_bounds__(256) void cvt_bf16_kernel(
    const float* __restrict__ Q, const float* __restrict__ K,
    const float* __restrict__ V, u16* __restrict__ Qb, u16* __restrict__ Kb,
    u16* __restrict__ Vb) {
  const int i = (blockIdx.x * 256 + threadIdx.x) * 4;
  if (i >= N * D) return;
  const float4 q = *reinterpret_cast<const float4*>(Q + i);
  const float4 k = *reinterpret_cast<const float4*>(K + i);
  const float4 v = *reinterpret_cast<const float4*>(V + i);
  auto pack = [](float a, float b) -> unsigned int {
    u16 ua = __builtin_bit_cast(u16, (__bf16)a);
    u16 ub = __builtin_bit_cast(u16, (__bf16)b);
    return (unsigned int)ua | ((unsigned int)ub << 16);
  };
  uint2 qo = { pack(q.x, q.y), pack(q.z, q.w) };
  uint2 ko = { pack(k.x, k.y), pack(k.z, k.w) };
  uint2 vo = { pack(v.x, v.y), pack(v.z, v.w) };
  *reinterpret_cast<uint2*>(Qb + i) = qo;
  *reinterpret_cast<uint2*>(Kb + i) = ko;
  *reinterpret_cast<uint2*>(Vb + i) = vo;
}

// ---------------- main flash kernel ----------------
// grid: 128 q-groups * NS split-blocks (sp = blockIdx.x>>7), 256 threads.
// Each wave owns one 16-row Q tile; block processes keys [sp*kpb, (sp+1)*kpb).
// Per 64-key stage: stage V^T in LDS, 4 S-MFMAs (S^T = mfma(K,Q)), ONE
// 64-key online-softmax update (one max tree + 2 shfl, 16 exp2, one sum +
// 2 shfl, one rescale), then 4 PV MFMAs with P kept in registers.
__global__ __launch_bounds__(256) void flash_kernel(
    const u16* __restrict__ Qb, const u16* __restrict__ Kb,
    const u16* __restrict__ Vb, float* __restrict__ mP, float* __restrict__ lP,
    float* __restrict__ OP, int kpb) {
  __shared__ u16 Vt[32][68];  // V^T stage: [d][key], pad 64->68

  const int lane = threadIdx.x & 63;
  const int wave = threadIdx.x >> 6;
  const int a = lane & 15;   // q-col within tile
  const int g = lane >> 4;   // lane group 0..3
  const int qg = blockIdx.x & 127;
  const int sp = blockIdx.x >> 7;
  const int qr0 = qg * 64 + wave * 16;
  const int k0 = sp * kpb;

  const bf16x8 qf = *reinterpret_cast<const bf16x8*>(Qb + (qr0 + a) * D + g * 8);

  const f32x4 zero4 = {0.f, 0.f, 0.f, 0.f};
  f32x4 acc0 = zero4, acc1 = zero4;  // O^T tiles: d in [0,16), [16,32)
  float mrun = -INFINITY;            // running max (log2 domain)
  float lsum = 0.f;

  const int sk = threadIdx.x & 63;   // staging: key within stage
  const int dgr = threadIdx.x >> 6;  // staging: d-group (8 dims)

  for (int kb = k0; kb < k0 + kpb; kb += 64) {
    __syncthreads();
    {
      const uint4 vv = *reinterpret_cast<const uint4*>(Vb + (kb + sk) * D + dgr * 8);
      const unsigned int w[4] = {vv.x, vv.y, vv.z, vv.w};
#pragma unroll
      for (int j = 0; j < 4; ++j) {
        Vt[dgr * 8 + 2 * j][sk]     = (u16)(w[j] & 0xffffu);
        Vt[dgr * 8 + 2 * j + 1][sk] = (u16)(w[j] >> 16);
      }
    }
    __syncthreads();

    // ---- S for all 4 16-key tiles of this 64-key stage ----
    f32x4 s[4];
#pragma unroll
    for (int t = 0; t < 4; ++t) {
      const bf16x8 kf =
          *reinterpret_cast<const bf16x8*>(Kb + (kb + t * 16 + a) * D + g * 8);
      s[t] = __builtin_amdgcn_mfma_f32_16x16x32_bf16(kf, qf, zero4, 0, 0, 0);
      s[t] *= L2E;  // log2 domain
    }

    // ---- one online-softmax update for 64 keys ----
    float tm = -INFINITY;
#pragma unroll
    for (int t = 0; t < 4; ++t)
      tm = fmaxf(tm, fmaxf(fmaxf(s[t][0], s[t][1]), fmaxf(s[t][2], s[t][3])));
    tm = fmaxf(tm, __shfl_xor(tm, 16, 64));
    tm = fmaxf(tm, __shfl_xor(tm, 32, 64));
    const float mnew = fmaxf(mrun, tm);
    const float sc = __builtin_amdgcn_exp2f(mrun - mnew);  // first iter: 0
    mrun = mnew;

    float p[4][4];
    float ps = 0.f;
#pragma unroll
    for (int t = 0; t < 4; ++t) {
#pragma unroll
      for (int r = 0; r < 4; ++r) {
        p[t][r] = __builtin_amdgcn_exp2f(s[t][r] - mnew);
        ps += p[t][r];
      }
    }
    ps += __shfl_xor(ps, 16, 64);
    ps += __shfl_xor(ps, 32, 64);
    lsum = lsum * sc + ps;
    acc0 *= sc;
    acc1 *= sc;

    const bf16x8 pf0 = {(__bf16)p[0][0], (__bf16)p[0][1], (__bf16)p[0][2], (__bf16)p[0][3],
                        (__bf16)p[1][0], (__bf16)p[1][1], (__bf16)p[1][2], (__bf16)p[1][3]};
    const bf16x8 pf1 = {(__bf16)p[2][0], (__bf16)p[2][1], (__bf16)p[2][2], (__bf16)p[2][3],
                        (__bf16)p[3][0], (__bf16)p[3][1], (__bf16)p[3][2], (__bf16)p[3][3]};

    // ---- PV: slot i <-> k_rel = 32u + 4g + (i&3) + 16*(i>>2) ----
#pragma unroll
    for (int u = 0; u < 2; ++u) {
      const int c0 = u * 32 + g * 4;
      const bf16x4 v00 = *reinterpret_cast<const bf16x4*>(&Vt[a][c0]);
      const bf16x4 v01 = *reinterpret_cast<const bf16x4*>(&Vt[a][c0 + 16]);
      const bf16x4 v10 = *reinterpret_cast<const bf16x4*>(&Vt[16 + a][c0]);
      const bf16x4 v11 = *reinterpret_cast<const bf16x4*>(&Vt[16 + a][c0 + 16]);
      const bf16x8 va0 = __builtin_shufflevector(v00, v01, 0, 1, 2, 3, 4, 5, 6, 7);
      const bf16x8 va1 = __builtin_shufflevector(v10, v11, 0, 1, 2, 3, 4, 5, 6, 7);
      const bf16x8 pf = u ? pf1 : pf0;
      acc0 = __builtin_amdgcn_mfma_f32_16x16x32_bf16(va0, pf, acc0, 0, 0, 0);
      acc1 = __builtin_amdgcn_mfma_f32_16x16x32_bf16(va1, pf, acc1, 0, 0, 0);
    }
  }

  // store partials: lane holds O[d = 16h + 4g + r][q = qr0 + a]
  float* obase = OP + (size_t)(sp * N + qr0 + a) * D;
#pragma unroll
  for (int r = 0; r < 4; ++r) {
    obase[4 * g + r] = acc0[r];
    obase[16 + 4 * g + r] = acc1[r];
  }
  if (g == 0) {
    mP[sp * N + qr0 + a] = mrun;
    lP[sp * N + qr0 + a] = lsum;
  }
}

// ---------------- combine splits ----------------
template <int NS>
__global__ __launch_bounds__(256) void combine_kernel(
    const float* __restrict__ mP, const float* __restrict__ lP,
    const float* __restrict__ OP, float* __restrict__ out) {
  const int idx = blockIdx.x * 256 + threadIdx.x;
  if (idx >= N * D) return;
  const int q = idx >> 5;
  float m[NS];
  float M = -INFINITY;
#pragma unroll
  for (int s = 0; s < NS; ++s) {
    m[s] = mP[s * N + q];
    M = fmaxf(M, m[s]);
  }
  float L = 0.f, o = 0.f;
#pragma unroll
  for (int s = 0; s < NS; ++s) {
    const float w = __builtin_amdgcn_exp2f(m[s] - M);
    L += w * lP[s * N + q];
    o += w * OP[(size_t)s * N * D + idx];
  }
  out[idx] = o / L;
}

extern "C" void kernel_launch(void* const* d_in, const int* in_sizes, int n_in,
                              void* d_out, int out_size, void* d_ws, size_t ws_size,
                              hipStream_t stream) {
  const float* Q = (const float*)d_in[0];
  const float* K = (const float*)d_in[1];
  const float* V = (const float*)d_in[2];
  float* out = (float*)d_out;

  // pick the largest K-split that fits in ws
  const size_t base = (size_t)3 * N * D * sizeof(u16);
  const size_t per_split = (size_t)N * 2 * sizeof(float) + (size_t)N * D * sizeof(float);
  int ns = 16;
  while (ns > 4 && base + (size_t)ns * per_split > ws_size) ns >>= 1;

  u16* Qb = (u16*)d_ws;
  u16* Kb = Qb + N * D;
  u16* Vb = Kb + N * D;
  float* mP = (float*)(Vb + N * D);
  float* lP = mP + ns * N;
  float* OP = lP + ns * N;

  cvt_bf16_kernel<<<(N * D) / (256 * 4), 256, 0, stream>>>(Q, K, V, Qb, Kb, Vb);
  flash_kernel<<<128 * ns, 256, 0, stream>>>(Qb, Kb, Vb, mP, lP, OP, N / ns);
  switch (ns) {
    case 16: combine_kernel<16><<<(N * D) / 256, 256, 0, stream>>>(mP, lP, OP, out); break;
    case 8:  combine_kernel<8><<<(N * D) / 256, 256, 0, stream>>>(mP, lP, OP, out); break;
    default: combine_kernel<4><<<(N * D) / 256, 256, 0, stream>>>(mP, lP, OP, out); break;
  }
}